// Round 10
// baseline (3479.724 us; speedup 1.0000x reference)
//
#include <hip/hip_runtime.h>
#include <math.h>

#define NB    256
#define HDIM  512
#define LDIM  32
#define ADIM  200
#define NOUTV 8
#define NSTEP 256
#define NTHR  512
#define NWG   256
#define WPG   16
#define SCST  21

typedef __attribute__((ext_vector_type(8))) short sh8;
typedef __attribute__((ext_vector_type(4))) float f4;

union FU { uint4 u; sh8 s; };

__device__ __forceinline__ float b2f(unsigned int low16) { return __uint_as_float(low16 << 16); }

__device__ __forceinline__ void group_barrier(unsigned int* ctr, unsigned int target) {
  __syncthreads();
  if (threadIdx.x == 0) {
    __hip_atomic_fetch_add(ctr, 1u, __ATOMIC_RELEASE, __HIP_MEMORY_SCOPE_AGENT);
    while (__hip_atomic_load(ctr, __ATOMIC_ACQUIRE, __HIP_MEMORY_SCOPE_AGENT) < target) {
      __builtin_amdgcn_s_sleep(1);
    }
  }
  __syncthreads();
}

__global__ void __launch_bounds__(NTHR, 1)
sym_kernel(const int* __restrict__ instr,      // (8,256)
           const int* __restrict__ trueact,    // (33,256)
           const float* __restrict__ isv,      // (200,)
           const float* __restrict__ prim_emb, // (16,200)
           const float* __restrict__ gate_w,   // (1,128)
           const float* __restrict__ gate_b,   // (1,)
           const float* __restrict__ w_hh,     // (1536,512)
           const float* __restrict__ b_ih,     // (1536,)
           const float* __restrict__ b_hh,     // (1536,)
           const float* __restrict__ out_w,    // (8,200)
           const float* __restrict__ out_b,    // (8,)
           float* __restrict__ outp,           // 65536 + 8192
           unsigned int* __restrict__ ctrs,
           unsigned int* __restrict__ hbuf)    // 2 * 256 * 512 packed u32 (hi16|lo16)
{
  const int tid  = threadIdx.x;
  const int lane = tid & 63, wv = tid >> 6;

  __shared__ __align__(16) unsigned short sHi[16 * 512];   // h hi-plane, XOR-swizzled
  __shared__ __align__(16) unsigned short sLo[16 * 512];   // h lo-plane
  __shared__ float sC[96 * SCST];                          // GEMM output r/z/n pre-acts
  __shared__ __align__(16) float sSV[LDIM * ADIM];         // my batch's scratch
  __shared__ __align__(16) float sNV[ADIM];
  __shared__ float sSKt[128 * 32];                         // SK^T [k][l] (prologue only)
  __shared__ __align__(16) float sPE[16 * ADIM];           // primitive_emb cache
  __shared__ float sAR[LDIM], sAW[LDIM];
  __shared__ float sGate;
  __shared__ unsigned int sMeta;

  // ---- XCD rendezvous: guarantee group = 16 wgs on ONE physical XCD ----
  // 256 wgs, 1 wg/CU (96KB LDS), 32 CUs/XCD -> each XCD hosts exactly 32 wgs.
  // Claim a rank within my XCD; two groups of 16 per XCD. Output is
  // assignment-invariant (every (gidx,jc) claimed exactly once).
  if (tid == 0) {
    unsigned int xcc;
    asm volatile("s_getreg_b32 %0, hwreg(HW_REG_XCC_ID, 0, 32)" : "=s"(xcc));
    xcc &= 7u;
    unsigned int r = __hip_atomic_fetch_add(ctrs + 512 + xcc * 32, 1u,
                                            __ATOMIC_RELAXED, __HIP_MEMORY_SCOPE_AGENT);
    sMeta = (xcc << 8) | (r & 31u);
  }

  // ---- gidx-independent prologue fills (overlap the rendezvous atomic) ----
  for (int i = tid; i < 128 * 32; i += NTHR) {
    const int k = i >> 5, l = i & 31;
    const float div = expf((float)(k & ~1) * (-9.210340371976184f / 128.0f));
    const float ang = (float)l * div;
    sSKt[i] = (k & 1) ? cosf(ang) : sinf(ang);
  }
  for (int i = tid; i < 16 * ADIM; i += NTHR) sPE[i] = prim_emb[i];
  for (int i = tid; i < LDIM * ADIM; i += NTHR) sSV[i] = isv[i % ADIM];
  __syncthreads();   // sSKt + sMeta ready

  const unsigned int meta = sMeta;
  const int gidx = (int)(((meta >> 8) << 1) | ((meta >> 4) & 1));  // xcc*2 + (r>>4)
  const int jc   = (int)(meta & 15u);
  const int myb  = (gidx << 4) | jc;

  unsigned int* ctr = ctrs + (gidx << 5);   // one 128B cacheline per group (XCD-local)

  // ---- per-thread loop invariants ----
  unsigned int wordpack = 0;
  #pragma unroll
  for (int wi = 0; wi < 8; ++wi)
    wordpack |= ((unsigned)instr[wi * NB + myb] & 15u) << (4 * wi);

  const int jj_t = (jc << 5) | (tid & 31);   // my combine j
  const float bi0 = b_ih[jj_t], bi1 = b_ih[512 + jj_t], bi2 = b_ih[1024 + jj_t];
  const float bh0 = b_hh[jj_t], bh1 = b_hh[512 + jj_t], bh2 = b_hh[1024 + jj_t];

  {
    unsigned int* h0 = hbuf + (size_t)myb * HDIM;
    for (int k = tid; k < HDIM; k += NTHR) h0[k] = (k & 1) ? 0x3F800000u : 0u;  // bf16(1.0)|0
  }

  // ---- shared register file: weights (wv<6) / SK column (wv6) / gate_w (wv7) ----
  unsigned int reg[128];
  if (wv < 6) {
    const int n = lane & 15, quad = lane >> 4;
    const int row96 = (wv << 4) | n;
    const int g = row96 >> 5;
    const int jj = (jc << 5) | (row96 & 31);
    const float* wrow = w_hh + (size_t)(g * 512 + jj) * 512;
    #pragma unroll
    for (int kk = 0; kk < 16; ++kk) {
      const float4 w0 = *(const float4*)(wrow + kk * 32 + quad * 8);
      const float4 w1 = *(const float4*)(wrow + kk * 32 + quad * 8 + 4);
      float e[8] = {w0.x, w0.y, w0.z, w0.w, w1.x, w1.y, w1.z, w1.w};
      unsigned int hi16[8], lo16[8];
      #pragma unroll
      for (int t = 0; t < 8; ++t) {
        const unsigned int b = __float_as_uint(e[t]);
        hi16[t] = b >> 16;
        const float rest = e[t] - __uint_as_float(b & 0xFFFF0000u);
        lo16[t] = __float_as_uint(rest) >> 16;
      }
      #pragma unroll
      for (int p = 0; p < 4; ++p) {
        reg[kk * 4 + p]      = hi16[2 * p] | (hi16[2 * p + 1] << 16);
        reg[64 + kk * 4 + p] = lo16[2 * p] | (lo16[2 * p + 1] << 16);
      }
    }
  } else if (wv == 6) {
    const int l = lane & 31;
    #pragma unroll
    for (int k = 0; k < 128; ++k) reg[k] = __float_as_uint(sSKt[k * 32 + l]);
  } else {
    reg[0] = __float_as_uint(gate_w[2 * lane]);
    reg[1] = __float_as_uint(gate_w[2 * lane + 1]);
  }

  group_barrier(ctr, WPG);   // h0 of all group batches visible

  const float gbias = gate_b[0];
  unsigned int bar = 2;

  for (int step = 0; step < NSTEP; ++step, ++bar) {
    const unsigned int* hc = hbuf + (size_t)(step & 1) * (NB * HDIM);
    unsigned int*       hn = hbuf + (size_t)((step & 1) ^ 1) * (NB * HDIM);

    // ---- stage packed h -> swizzled hi/lo planes (1024 chunks of 8 elems) ----
    {
      const uint4* src = (const uint4*)(hc + (size_t)(gidx << 4) * HDIM);
      #pragma unroll
      for (int it = 0; it < 2; ++it) {
        const int c   = tid + it * NTHR;          // 0..1023
        const int row = c >> 6;
        const int kb  = (c & 63) << 4;
        const uint4 x0 = src[c * 2], x1 = src[c * 2 + 1];
        const int off = row * 1024 + (kb ^ ((row & 7) << 4));
        *(uint4*)((char*)sHi + off) = make_uint4(
          (x0.x >> 16) | (x0.y & 0xFFFF0000u),
          (x0.z >> 16) | (x0.w & 0xFFFF0000u),
          (x1.x >> 16) | (x1.y & 0xFFFF0000u),
          (x1.z >> 16) | (x1.w & 0xFFFF0000u));
        *(uint4*)((char*)sLo + off) = make_uint4(
          (x0.x & 0xFFFFu) | (x0.y << 16),
          (x0.z & 0xFFFFu) | (x0.w << 16),
          (x1.x & 0xFFFFu) | (x1.y << 16),
          (x1.z & 0xFFFFu) | (x1.w << 16));
      }
    }
    __syncthreads();

    // ---- region 1: MFMA hi-only (waves 0-5) || attention (wave 6) || gate (wave 7) ----
    if (wv < 6) {
      const int n = lane & 15, quad = lane >> 4;
      const int sw = (n & 7) << 4;
      f4 a0 = {0.f, 0.f, 0.f, 0.f}, a1 = a0;
      #pragma unroll
      for (int kk = 0; kk < 16; ++kk) {
        const int off = n * 1024 + (((kk << 6) | (quad << 4)) ^ sw);
        FU fah, fbh, fbl;
        fah.u = *(const uint4*)((const char*)sHi + off);
        fbh.u = make_uint4(reg[kk * 4], reg[kk * 4 + 1], reg[kk * 4 + 2], reg[kk * 4 + 3]);
        fbl.u = make_uint4(reg[64 + kk * 4], reg[64 + kk * 4 + 1], reg[64 + kk * 4 + 2], reg[64 + kk * 4 + 3]);
        a0 = __builtin_amdgcn_mfma_f32_16x16x32_bf16(fah.s, fbh.s, a0, 0, 0, 0);
        a1 = __builtin_amdgcn_mfma_f32_16x16x32_bf16(fah.s, fbl.s, a1, 0, 0, 0);
      }
      const int row96 = (wv << 4) | n;
      #pragma unroll
      for (int i = 0; i < 4; ++i)
        sC[row96 * SCST + (quad << 2) + i] = a0[i] + a1[i];
    } else if (wv == 6) {
      const int l = lane & 31, sel = lane >> 5;
      const int sw = (jc & 7) << 4;
      float ac0 = 0.f, ac1 = 0.f, ac2 = 0.f, ac3 = 0.f;
      #pragma unroll
      for (int c = 0; c < 32; ++c) {
        const int kbyte = (128 + sel * 128 + c * 4) * 2;
        const int off = jc * 1024 + (kbyte ^ sw);
        const uint2 hb = *(const uint2*)((const char*)sHi + off);
        const uint2 lb = *(const uint2*)((const char*)sLo + off);
        ac0 = fmaf(b2f(hb.x & 0xFFFFu) + b2f(lb.x & 0xFFFFu), __uint_as_float(reg[c * 4]), ac0);
        ac1 = fmaf(__uint_as_float(hb.x & 0xFFFF0000u) + __uint_as_float(lb.x & 0xFFFF0000u),
                   __uint_as_float(reg[c * 4 + 1]), ac1);
        ac2 = fmaf(b2f(hb.y & 0xFFFFu) + b2f(lb.y & 0xFFFFu), __uint_as_float(reg[c * 4 + 2]), ac2);
        ac3 = fmaf(__uint_as_float(hb.y & 0xFFFF0000u) + __uint_as_float(lb.y & 0xFFFF0000u),
                   __uint_as_float(reg[c * 4 + 3]), ac3);
      }
      float acc = (ac0 + ac1) + (ac2 + ac3);
      float mx = acc;
      #pragma unroll
      for (int m = 1; m < 32; m <<= 1) mx = fmaxf(mx, __shfl_xor(mx, m, 32));
      const float ev = __expf(acc - mx);
      float s = ev;
      #pragma unroll
      for (int m = 1; m < 32; m <<= 1) s += __shfl_xor(s, m, 32);
      (sel ? sAW : sAR)[l] = ev / s;
    } else {
      const int sw = (jc & 7) << 4;
      const int off = jc * 1024 + ((768 + 4 * lane) ^ sw);
      const unsigned int hb = *(const unsigned int*)((const char*)sHi + off);
      const unsigned int lb = *(const unsigned int*)((const char*)sLo + off);
      const float e0 = b2f(hb & 0xFFFFu) + b2f(lb & 0xFFFFu);
      const float e1 = __uint_as_float(hb & 0xFFFF0000u) + __uint_as_float(lb & 0xFFFF0000u);
      float part = fmaf(e0, __uint_as_float(reg[0]), e1 * __uint_as_float(reg[1]));
      #pragma unroll
      for (int m = 1; m < 64; m <<= 1) part += __shfl_xor(part, m, 64);
      if (lane == 0) sGate = 1.0f / (1.0f + __expf(-(part + gbias)));
    }
    __syncthreads();

    // ---- region 2: GRU combine + h store (all threads) ----
    {
      const int b = tid >> 5, jcol = tid & 31;
      const float accR = sC[jcol * SCST + b];
      const float accZ = sC[(32 + jcol) * SCST + b];
      const float accN = sC[(64 + jcol) * SCST + b];
      const float r  = 1.f / (1.f + __expf(-(accR + bh0 + bi0)));
      const float z  = 1.f / (1.f + __expf(-(accZ + bh1 + bi1)));
      const float nn = tanhf(fmaf(r, accN + bh2, bi2));
      const int hoff = b * 1024 + ((jj_t * 2) ^ ((b & 7) << 4));
      const float hold = b2f(*(const unsigned short*)((const char*)sHi + hoff))
                       + b2f(*(const unsigned short*)((const char*)sLo + hoff));
      const float hnew = fmaf(z, hold - nn, nn);
      const unsigned int hibits = __float_as_uint(hnew) & 0xFFFF0000u;
      const float rest = hnew - __uint_as_float(hibits);
      const unsigned int lobits = __float_as_uint(rest) >> 16;
      hn[(size_t)((gidx << 4) + b) * HDIM + jj_t] = hibits | lobits;
    }
    if (tid < ADIM) {
      const int word = (wordpack >> ((step >> 5) << 2)) & 15u;
      float rv = 0.f;
      #pragma unroll 8
      for (int l = 0; l < LDIM; ++l) rv = fmaf(sAR[l], sSV[l * ADIM + tid], rv);
      const float g = sGate;
      sNV[tid] = fmaf(g, sPE[word * ADIM + tid], (1.f - g) * rv);
    }
    __syncthreads();

    // ---- region 3: scratch update (vectorized) ----
    {
      const f4* nv4 = (const f4*)sNV;
      f4* sv4 = (f4*)sSV;
      #pragma unroll
      for (int it = 0; it < 4; ++it) {
        const int s4 = tid + it * NTHR;
        if (s4 < 1600) {
          const int l = s4 / 50, a4 = s4 - l * 50;
          const float w = sAW[l];
          const f4 nv = nv4[a4];
          f4 sv = sv4[s4];
          sv.x = fmaf(w, nv.x - sv.x, sv.x);
          sv.y = fmaf(w, nv.y - sv.y, sv.y);
          sv.z = fmaf(w, nv.z - sv.z, sv.z);
          sv.w = fmaf(w, nv.w - sv.w, sv.w);
          sv4[s4] = sv;
        }
      }
    }

    group_barrier(ctr, bar * WPG);
  }

  // ---- epilogue: actions = log_softmax(sv @ out_w.T + out_b), (b, v, l) ----
  if (tid < 256) {
    const int l = tid >> 3, v = tid & 7;
    const float* svrow = sSV + l * ADIM;
    const float* wrow  = out_w + v * ADIM;
    float acc = out_b[v];
    #pragma unroll 8
    for (int a = 0; a < ADIM; ++a) acc = fmaf(svrow[a], wrow[a], acc);
    float mx = acc;
    #pragma unroll
    for (int m = 1; m < 8; m <<= 1) mx = fmaxf(mx, __shfl_xor(mx, m, 8));
    const float e = __expf(acc - mx);
    float s = e;
    #pragma unroll
    for (int m = 1; m < 8; m <<= 1) s += __shfl_xor(s, m, 8);
    outp[(size_t)myb * (NOUTV * LDIM) + v * LDIM + l] = acc - mx - logf(s);
  }
  if (tid < LDIM) {
    outp[NB * NOUTV * LDIM + myb * LDIM + tid] = (float)trueact[(tid + 1) * NB + myb];
  }
}

extern "C" void kernel_launch(void* const* d_in, const int* in_sizes, int n_in,
                              void* d_out, int out_size, void* d_ws, size_t ws_size,
                              hipStream_t stream) {
  const int*   instr   = (const int*)d_in[0];
  const int*   trueact = (const int*)d_in[1];
  const float* isv     = (const float*)d_in[2];
  // d_in[3] = program_emb (unused by reference math)
  const float* prim    = (const float*)d_in[4];
  const float* gate_w  = (const float*)d_in[5];
  const float* gate_b  = (const float*)d_in[6];
  // d_in[7] = w_ih (multiplied by zeros; only b_ih matters)
  const float* w_hh    = (const float*)d_in[8];
  const float* b_ih    = (const float*)d_in[9];
  const float* b_hh    = (const float*)d_in[10];
  const float* out_w   = (const float*)d_in[11];
  const float* out_b   = (const float*)d_in[12];
  float* outp = (float*)d_out;

  // ws layout: [0..2047] group barrier ctrs (16 x 128B) | [2048..3071] XCD
  // rendezvous ctrs (8 x 128B) | [4096..] hbuf (2 * 256 * 512 u32 = 1 MB)
  unsigned int* ctrs = (unsigned int*)d_ws;
  unsigned int* hbuf = (unsigned int*)((char*)d_ws + 4096);

  hipMemsetAsync(d_ws, 0, 4096, stream);

  void* args[] = { (void*)&instr, (void*)&trueact, (void*)&isv, (void*)&prim,
                   (void*)&gate_w, (void*)&gate_b, (void*)&w_hh, (void*)&b_ih,
                   (void*)&b_hh, (void*)&out_w, (void*)&out_b, (void*)&outp,
                   (void*)&ctrs, (void*)&hbuf };
  hipLaunchCooperativeKernel((const void*)sym_kernel, dim3(NWG), dim3(NTHR),
                             args, 0, stream);
}

// Round 11
// 3109.676 us; speedup vs baseline: 1.1190x; 1.1190x over previous
//
#include <hip/hip_runtime.h>
#include <math.h>

#define NB    256
#define HDIM  512
#define LDIM  32
#define ADIM  200
#define NOUTV 8
#define NSTEP 256
#define NTHR  512
#define NWG   256
#define WPG   16
#define SCST  21

typedef __attribute__((ext_vector_type(8))) short sh8;
typedef __attribute__((ext_vector_type(4))) float f4;

union FU { uint4 u; sh8 s; };

__device__ __forceinline__ float b2f(unsigned int low16) { return __uint_as_float(low16 << 16); }

// Barrier: release add, RELAXED poll (no per-iteration buffer_inv!), one acquire.
__device__ __forceinline__ void group_barrier(unsigned int* ctr, unsigned int target) {
  __syncthreads();
  if (threadIdx.x == 0) {
    __hip_atomic_fetch_add(ctr, 1u, __ATOMIC_RELEASE, __HIP_MEMORY_SCOPE_AGENT);
    while (__hip_atomic_load(ctr, __ATOMIC_RELAXED, __HIP_MEMORY_SCOPE_AGENT) < target) {
      __builtin_amdgcn_s_sleep(1);
    }
    unsigned int v = __hip_atomic_load(ctr, __ATOMIC_ACQUIRE, __HIP_MEMORY_SCOPE_AGENT);
    asm volatile("" :: "v"(v));   // keep the single acquire (L1 invalidate) alive
  }
  __syncthreads();
}

__global__ void __launch_bounds__(NTHR, 1)
sym_kernel(const int* __restrict__ instr,      // (8,256)
           const int* __restrict__ trueact,    // (33,256)
           const float* __restrict__ isv,      // (200,)
           const float* __restrict__ prim_emb, // (16,200)
           const float* __restrict__ gate_w,   // (1,128)
           const float* __restrict__ gate_b,   // (1,)
           const float* __restrict__ w_hh,     // (1536,512)
           const float* __restrict__ b_ih,     // (1536,)
           const float* __restrict__ b_hh,     // (1536,)
           const float* __restrict__ out_w,    // (8,200)
           const float* __restrict__ out_b,    // (8,)
           float* __restrict__ outp,           // 65536 + 8192
           unsigned int* __restrict__ ctrs,
           unsigned int* __restrict__ hbuf)    // 2 * 256 * 512 packed u32 (hi16|lo16)
{
  const int tid  = threadIdx.x;
  const int lane = tid & 63, wv = tid >> 6;

  __shared__ __align__(16) unsigned short sHi[16 * 512];   // h hi-plane, XOR-swizzled
  __shared__ __align__(16) unsigned short sLo[16 * 512];   // lo-plane (only row jc written)
  __shared__ float sC[96 * SCST];                          // GEMM output r/z/n pre-acts
  __shared__ __align__(16) float sSV[LDIM * ADIM];         // my batch's scratch
  __shared__ float sSKt[128 * 32];                         // SK^T [k][l] (prologue only)
  __shared__ __align__(16) float sPE[16 * ADIM];           // primitive_emb cache
  __shared__ float sAR[LDIM], sAW[LDIM];
  __shared__ float sGate;
  __shared__ unsigned int sMeta;

  // ---- XCD rendezvous: group = 16 wgs on ONE physical XCD (verified R10) ----
  if (tid == 0) {
    unsigned int xcc;
    asm volatile("s_getreg_b32 %0, hwreg(HW_REG_XCC_ID, 0, 32)" : "=s"(xcc));
    xcc &= 7u;
    unsigned int r = __hip_atomic_fetch_add(ctrs + 512 + xcc * 32, 1u,
                                            __ATOMIC_RELAXED, __HIP_MEMORY_SCOPE_AGENT);
    sMeta = (xcc << 8) | (r & 31u);
  }

  // ---- gidx-independent prologue fills (overlap the rendezvous atomic) ----
  for (int i = tid; i < 128 * 32; i += NTHR) {
    const int k = i >> 5, l = i & 31;
    const float div = expf((float)(k & ~1) * (-9.210340371976184f / 128.0f));
    const float ang = (float)l * div;
    sSKt[i] = (k & 1) ? cosf(ang) : sinf(ang);
  }
  for (int i = tid; i < 16 * ADIM; i += NTHR) sPE[i] = prim_emb[i];
  for (int i = tid; i < LDIM * ADIM; i += NTHR) sSV[i] = isv[i % ADIM];
  __syncthreads();   // sSKt + sMeta ready

  const unsigned int meta = sMeta;
  const int gidx = (int)(((meta >> 8) << 1) | ((meta >> 4) & 1));  // xcc*2 + (r>>4)
  const int jc   = (int)(meta & 15u);
  const int myb  = (gidx << 4) | jc;

  unsigned int* ctr = ctrs + (gidx << 5);   // one 128B cacheline per group (XCD-local)

  // ---- per-thread loop invariants ----
  unsigned int wordpack = 0;
  #pragma unroll
  for (int wi = 0; wi < 8; ++wi)
    wordpack |= ((unsigned)instr[wi * NB + myb] & 15u) << (4 * wi);

  const int jj_t = (jc << 5) | (tid & 31);   // my combine j
  const float bi0 = b_ih[jj_t], bi1 = b_ih[512 + jj_t], bi2 = b_ih[1024 + jj_t];
  const float bh0 = b_hh[jj_t], bh1 = b_hh[512 + jj_t], bh2 = b_hh[1024 + jj_t];
  float hold_reg = (jj_t & 1) ? 1.0f : 0.0f;   // pe[0] tiled; carried in f32 all steps

  {
    unsigned int* h0 = hbuf + (size_t)myb * HDIM;
    for (int k = tid; k < HDIM; k += NTHR) h0[k] = (k & 1) ? 0x3F800000u : 0u;  // bf16(1.0)|0
  }

  // ---- shared register file: weights (wv<6) / SK column (wv6) / gate_w (wv7) ----
  // All reg[] accesses static (rule #20).
  unsigned int reg[128];
  if (wv < 6) {
    const int n = lane & 15, quad = lane >> 4;
    const int row96 = (wv << 4) | n;
    const int g = row96 >> 5;
    const int jj = (jc << 5) | (row96 & 31);
    const float* wrow = w_hh + (size_t)(g * 512 + jj) * 512;
    #pragma unroll
    for (int kk = 0; kk < 16; ++kk) {
      const float4 w0 = *(const float4*)(wrow + kk * 32 + quad * 8);
      const float4 w1 = *(const float4*)(wrow + kk * 32 + quad * 8 + 4);
      float e[8] = {w0.x, w0.y, w0.z, w0.w, w1.x, w1.y, w1.z, w1.w};
      unsigned int hi16[8], lo16[8];
      #pragma unroll
      for (int t = 0; t < 8; ++t) {
        const unsigned int b = __float_as_uint(e[t]);
        hi16[t] = b >> 16;
        const float rest = e[t] - __uint_as_float(b & 0xFFFF0000u);
        lo16[t] = __float_as_uint(rest) >> 16;
      }
      #pragma unroll
      for (int p = 0; p < 4; ++p) {
        reg[kk * 4 + p]      = hi16[2 * p] | (hi16[2 * p + 1] << 16);
        reg[64 + kk * 4 + p] = lo16[2 * p] | (lo16[2 * p + 1] << 16);
      }
    }
  } else if (wv == 6) {
    const int l = lane & 31;
    #pragma unroll
    for (int k = 0; k < 128; ++k) reg[k] = __float_as_uint(sSKt[k * 32 + l]);
  } else {
    reg[0] = __float_as_uint(gate_w[2 * lane]);
    reg[1] = __float_as_uint(gate_w[2 * lane + 1]);
  }

  group_barrier(ctr, WPG);   // h0 of all group batches visible

  const float gbias = gate_b[0];
  unsigned int bar = 2;

  for (int step = 0; step < NSTEP; ++step, ++bar) {
    const unsigned int* hc = hbuf + (size_t)(step & 1) * (NB * HDIM);
    unsigned int*       hn = hbuf + (size_t)((step & 1) ^ 1) * (NB * HDIM);

    // ---- stage: hi-plane all rows, lo-plane only row jc (wave-uniform branch) ----
    {
      const uint4* src = (const uint4*)(hc + (size_t)(gidx << 4) * HDIM);
      #pragma unroll
      for (int it = 0; it < 2; ++it) {
        const int c   = tid + it * NTHR;          // 0..1023
        const int row = c >> 6;
        const int kb  = (c & 63) << 4;
        const uint4 x0 = src[c * 2], x1 = src[c * 2 + 1];
        const int off = row * 1024 + (kb ^ ((row & 7) << 4));
        *(uint4*)((char*)sHi + off) = make_uint4(
          (x0.x >> 16) | (x0.y & 0xFFFF0000u),
          (x0.z >> 16) | (x0.w & 0xFFFF0000u),
          (x1.x >> 16) | (x1.y & 0xFFFF0000u),
          (x1.z >> 16) | (x1.w & 0xFFFF0000u));
        if (row == jc)
          *(uint4*)((char*)sLo + off) = make_uint4(
            (x0.x & 0xFFFFu) | (x0.y << 16),
            (x0.z & 0xFFFFu) | (x0.w << 16),
            (x1.x & 0xFFFFu) | (x1.y << 16),
            (x1.z & 0xFFFFu) | (x1.w << 16));
      }
    }
    __syncthreads();

    // ---- region 1: MFMA hi-only (waves 0-5) || attention (wave 6) || gate (wave 7) ----
    if (wv < 6) {
      const int n = lane & 15, quad = lane >> 4;
      const int sw = (n & 7) << 4;
      f4 a0 = {0.f, 0.f, 0.f, 0.f}, a1 = a0;
      #pragma unroll
      for (int kk = 0; kk < 16; ++kk) {
        const int off = n * 1024 + (((kk << 6) | (quad << 4)) ^ sw);
        FU fah, fbh, fbl;
        fah.u = *(const uint4*)((const char*)sHi + off);
        fbh.u = make_uint4(reg[kk * 4], reg[kk * 4 + 1], reg[kk * 4 + 2], reg[kk * 4 + 3]);
        fbl.u = make_uint4(reg[64 + kk * 4], reg[64 + kk * 4 + 1], reg[64 + kk * 4 + 2], reg[64 + kk * 4 + 3]);
        a0 = __builtin_amdgcn_mfma_f32_16x16x32_bf16(fah.s, fbh.s, a0, 0, 0, 0);
        a1 = __builtin_amdgcn_mfma_f32_16x16x32_bf16(fah.s, fbl.s, a1, 0, 0, 0);
      }
      const int row96 = (wv << 4) | n;
      #pragma unroll
      for (int i = 0; i < 4; ++i)
        sC[row96 * SCST + (quad << 2) + i] = a0[i] + a1[i];
    } else if (wv == 6) {
      const int l = lane & 31, sel = lane >> 5;
      const int sw = (jc & 7) << 4;
      float ac0 = 0.f, ac1 = 0.f, ac2 = 0.f, ac3 = 0.f;
      #pragma unroll
      for (int c = 0; c < 32; ++c) {
        const int kbyte = (128 + sel * 128 + c * 4) * 2;
        const int off = jc * 1024 + (kbyte ^ sw);
        const uint2 hb = *(const uint2*)((const char*)sHi + off);
        const uint2 lb = *(const uint2*)((const char*)sLo + off);
        ac0 = fmaf(b2f(hb.x & 0xFFFFu) + b2f(lb.x & 0xFFFFu), __uint_as_float(reg[c * 4]), ac0);
        ac1 = fmaf(__uint_as_float(hb.x & 0xFFFF0000u) + __uint_as_float(lb.x & 0xFFFF0000u),
                   __uint_as_float(reg[c * 4 + 1]), ac1);
        ac2 = fmaf(b2f(hb.y & 0xFFFFu) + b2f(lb.y & 0xFFFFu), __uint_as_float(reg[c * 4 + 2]), ac2);
        ac3 = fmaf(__uint_as_float(hb.y & 0xFFFF0000u) + __uint_as_float(lb.y & 0xFFFF0000u),
                   __uint_as_float(reg[c * 4 + 3]), ac3);
      }
      float acc = (ac0 + ac1) + (ac2 + ac3);
      float mx = acc;
      #pragma unroll
      for (int m = 1; m < 32; m <<= 1) mx = fmaxf(mx, __shfl_xor(mx, m, 32));
      const float ev = __expf(acc - mx);
      float s = ev;
      #pragma unroll
      for (int m = 1; m < 32; m <<= 1) s += __shfl_xor(s, m, 32);
      (sel ? sAW : sAR)[l] = ev / s;
    } else {
      const int sw = (jc & 7) << 4;
      const int off = jc * 1024 + ((768 + 4 * lane) ^ sw);
      const unsigned int hb = *(const unsigned int*)((const char*)sHi + off);
      const unsigned int lb = *(const unsigned int*)((const char*)sLo + off);
      const float e0 = b2f(hb & 0xFFFFu) + b2f(lb & 0xFFFFu);
      const float e1 = __uint_as_float(hb & 0xFFFF0000u) + __uint_as_float(lb & 0xFFFF0000u);
      float part = fmaf(e0, __uint_as_float(reg[0]), e1 * __uint_as_float(reg[1]));
      #pragma unroll
      for (int m = 1; m < 64; m <<= 1) part += __shfl_xor(part, m, 64);
      if (lane == 0) sGate = 1.0f / (1.0f + __expf(-(part + gbias)));
    }
    __syncthreads();

    // ---- region 2: GRU combine + h store (hold in register); fused sv pass ----
    {
      const int b = tid >> 5, jcol = tid & 31;
      const float accR = sC[jcol * SCST + b];
      const float accZ = sC[(32 + jcol) * SCST + b];
      const float accN = sC[(64 + jcol) * SCST + b];
      const float r  = 1.f / (1.f + __expf(-(accR + bh0 + bi0)));
      const float z  = 1.f / (1.f + __expf(-(accZ + bh1 + bi1)));
      const float nn = tanhf(fmaf(r, accN + bh2, bi2));
      const float hnew = fmaf(z, hold_reg - nn, nn);
      hold_reg = hnew;
      const unsigned int hibits = __float_as_uint(hnew) & 0xFFFF0000u;
      const float rest = hnew - __uint_as_float(hibits);
      const unsigned int lobits = __float_as_uint(rest) >> 16;
      hn[(size_t)((gidx << 4) + b) * HDIM + jj_t] = hibits | lobits;
    }
    // fused A2+A3: thread a owns sv column a (no cross-thread hazard, no extra sync)
    if (tid < ADIM) {
      const int word = (wordpack >> ((step >> 5) << 2)) & 15u;
      const float g = sGate;
      const float pv = sPE[word * ADIM + tid];
      float svv[LDIM];
      float rv = 0.f;
      #pragma unroll
      for (int l = 0; l < LDIM; ++l) {
        svv[l] = sSV[l * ADIM + tid];
        rv = fmaf(sAR[l], svv[l], rv);
      }
      const float nv = fmaf(g, pv, (1.f - g) * rv);
      #pragma unroll
      for (int l = 0; l < LDIM; ++l)
        sSV[l * ADIM + tid] = fmaf(sAW[l], nv - svv[l], svv[l]);
    }

    group_barrier(ctr, bar * WPG);   // includes the pre-signal __syncthreads (drains h stores)
  }

  // ---- epilogue: actions = log_softmax(sv @ out_w.T + out_b), (b, v, l) ----
  if (tid < 256) {
    const int l = tid >> 3, v = tid & 7;
    const float* svrow = sSV + l * ADIM;
    const float* wrow  = out_w + v * ADIM;
    float acc = out_b[v];
    #pragma unroll 8
    for (int a = 0; a < ADIM; ++a) acc = fmaf(svrow[a], wrow[a], acc);
    float mx = acc;
    #pragma unroll
    for (int m = 1; m < 8; m <<= 1) mx = fmaxf(mx, __shfl_xor(mx, m, 8));
    const float e = __expf(acc - mx);
    float s = e;
    #pragma unroll
    for (int m = 1; m < 8; m <<= 1) s += __shfl_xor(s, m, 8);
    outp[(size_t)myb * (NOUTV * LDIM) + v * LDIM + l] = acc - mx - logf(s);
  }
  if (tid < LDIM) {
    outp[NB * NOUTV * LDIM + myb * LDIM + tid] = (float)trueact[(tid + 1) * NB + myb];
  }
}

extern "C" void kernel_launch(void* const* d_in, const int* in_sizes, int n_in,
                              void* d_out, int out_size, void* d_ws, size_t ws_size,
                              hipStream_t stream) {
  const int*   instr   = (const int*)d_in[0];
  const int*   trueact = (const int*)d_in[1];
  const float* isv     = (const float*)d_in[2];
  // d_in[3] = program_emb (unused by reference math)
  const float* prim    = (const float*)d_in[4];
  const float* gate_w  = (const float*)d_in[5];
  const float* gate_b  = (const float*)d_in[6];
  // d_in[7] = w_ih (multiplied by zeros; only b_ih matters)
  const float* w_hh    = (const float*)d_in[8];
  const float* b_ih    = (const float*)d_in[9];
  const float* b_hh    = (const float*)d_in[10];
  const float* out_w   = (const float*)d_in[11];
  const float* out_b   = (const float*)d_in[12];
  float* outp = (float*)d_out;

  // ws layout: [0..2047] group barrier ctrs (16 x 128B) | [2048..3071] XCD
  // rendezvous ctrs (8 x 128B) | [4096..] hbuf (2 * 256 * 512 u32 = 1 MB)
  unsigned int* ctrs = (unsigned int*)d_ws;
  unsigned int* hbuf = (unsigned int*)((char*)d_ws + 4096);

  hipMemsetAsync(d_ws, 0, 4096, stream);

  void* args[] = { (void*)&instr, (void*)&trueact, (void*)&isv, (void*)&prim,
                   (void*)&gate_w, (void*)&gate_b, (void*)&w_hh, (void*)&b_ih,
                   (void*)&b_hh, (void*)&out_w, (void*)&out_b, (void*)&outp,
                   (void*)&ctrs, (void*)&hbuf };
  hipLaunchCooperativeKernel((const void*)sym_kernel, dim3(NWG), dim3(NTHR),
                             args, 0, stream);
}